// Round 2
// baseline (378.807 us; speedup 1.0000x reference)
//
#include <hip/hip_runtime.h>
#include <stdint.h>

// CutOutput: per visit v (8192 total), stable descending argsort of D=1571
// f32 scores; emit index order, zeroing positions >= L where L = base[v].
//
// One workgroup per visit. Pack each element into a 43-bit key
//   key = (~orderable(f) << 11) | index
// orderable(f) is the sign-flip mapping (ascending uint <-> ascending float).
// Inverting makes ascending key == descending value; low 11 bits give
// ascending-index tie-break == JAX stable argsort of -x (bit-exact).
// Bitonic sort the padded 2048-key array in LDS (16 KB), then write
// index & prefix mask.
//
// ids collapses: ids = repeat(arange(P), T) sorted -> counts[p]==T,
// offsets[p]==p*T, so lens[flat v] == base[v]. No segment pass needed.

#define NSORT 2048
#define BLK   256

__global__ __launch_bounds__(BLK) void cutout_sort_kernel(
    const float* __restrict__ to_cut,
    const int*  __restrict__ base,
    int*        __restrict__ out,
    int D) {
  __shared__ uint64_t s[NSORT];
  const int    v   = blockIdx.x;
  const size_t off = (size_t)v * (size_t)D;
  const int    tid = threadIdx.x;

  // Load + pack. Pad with max key so padding sorts to the end (ascending).
  for (int i = tid; i < NSORT; i += BLK) {
    uint64_t key;
    if (i < D) {
      unsigned int u = __float_as_uint(to_cut[off + i]);
      u = (u & 0x80000000u) ? ~u : (u | 0x80000000u);  // ascending-orderable
      key = ((uint64_t)(~u) << 11) | (unsigned)i;      // invert -> descending
    } else {
      key = ~0ull;
    }
    s[i] = key;
  }
  __syncthreads();

  // Bitonic sort, ascending. Iterate over the NSORT/2 exchange pairs so all
  // lanes do useful work (no (i^j)>i masking).
  for (int k = 2; k <= NSORT; k <<= 1) {
    for (int j = k >> 1; j > 0; j >>= 1) {
      for (int m = tid; m < (NSORT / 2); m += BLK) {
        int i   = ((m & ~(j - 1)) << 1) | (m & (j - 1));
        int ixj = i | j;
        uint64_t a = s[i];
        uint64_t b = s[ixj];
        bool up = ((i & k) == 0);
        if ((a > b) == up) { s[i] = b; s[ixj] = a; }
      }
      __syncthreads();
    }
  }

  // Emit: rank r gets original index (key low 11 bits), zeroed for r >= L.
  const int L = base[v];
  for (int r = tid; r < D; r += BLK) {
    int idx = (int)(s[r] & 2047u);
    out[off + r] = (r < L) ? idx : 0;
  }
}

extern "C" void kernel_launch(void* const* d_in, const int* in_sizes, int n_in,
                              void* d_out, int out_size, void* d_ws, size_t ws_size,
                              hipStream_t stream) {
  const float* to_cut = (const float*)d_in[0];
  const int*   base   = (const int*)d_in[1];
  const int N = in_sizes[1];              // number of visits (P*T)
  const int D = in_sizes[0] / N;          // codes per visit

  cutout_sort_kernel<<<dim3(N), dim3(BLK), 0, stream>>>(
      to_cut, base, (int*)d_out, D);
}

// Round 3
// 328.264 us; speedup vs baseline: 1.1540x; 1.1540x over previous
//
#include <hip/hip_runtime.h>
#include <stdint.h>

// CutOutput: per visit v (8192), stable descending argsort of D=1571 f32
// scores; emit index order, zeroing ranks >= L = base[v].
//
// Key packing (bit-exact vs JAX stable argsort of -x):
//   key = (~orderable(f) << 11) | index   — ascending u64 == descending f32,
//   ties broken by ascending index.
//
// Bitonic-2048 restructured for register residency:
//   thread t owns elements 8t..8t+7 in VGPRs.
//   stride j in {1,2,4}   -> intra-thread register CE   (30 of 66 passes)
//   stride j in {8..256}  -> __shfl_xor with t^(j/8)    (33 passes, same wave)
//   stride j in {512,1024}-> LDS exchange, 3 passes only, transposed layout
//                            slot = o*256 + t so dump & partner read are
//                            unit-stride across lanes (conflict-free).
// 6 __syncthreads total (vs 66 in the all-LDS version).

#define BLK   256
#define NSORT 2048
#define EPT   8

__device__ __forceinline__ uint64_t shfl_xor_u64(uint64_t x, int m) {
  unsigned lo = (unsigned)__shfl_xor((int)(unsigned)x, m, 64);
  unsigned hi = (unsigned)__shfl_xor((int)(unsigned)(x >> 32), m, 64);
  return ((uint64_t)hi << 32) | lo;
}

__device__ __forceinline__ void ce(uint64_t& a, uint64_t& b, bool up) {
  uint64_t lo = (a < b) ? a : b;
  uint64_t hi = (a < b) ? b : a;
  a = up ? lo : hi;
  b = up ? hi : lo;
}

__global__ __launch_bounds__(BLK, 8) void cutout_sort_kernel(
    const float* __restrict__ to_cut,
    const int*  __restrict__ base,
    int*        __restrict__ out,
    int D) {
  __shared__ uint64_t lds[NSORT];
  const int    t   = threadIdx.x;
  const int    v   = blockIdx.x;
  const size_t off = (size_t)v * (size_t)D;

  // Load + pack. Pad (e >= D) with max key so padding sorts to the end.
  uint64_t r[EPT];
#pragma unroll
  for (int o = 0; o < EPT; ++o) {
    const int e = t * EPT + o;
    uint64_t key = ~0ull;
    if (e < D) {
      unsigned u = __float_as_uint(to_cut[off + e]);
      u = (u & 0x80000000u) ? ~u : (u | 0x80000000u);  // ascending-orderable
      key = ((uint64_t)(unsigned)(~u) << 11) | (unsigned)e;
    }
    r[o] = key;
  }

  // ---- k=2 (j=1): dir = ((i&2)==0), i = 8t+o -> depends on o only ----
  ce(r[0], r[1], true);  ce(r[2], r[3], false);
  ce(r[4], r[5], true);  ce(r[6], r[7], false);
  // ---- k=4 (j=2,1): dir = ((i&4)==0) -> o<4 up, o>=4 down ----
  ce(r[0], r[2], true);  ce(r[1], r[3], true);
  ce(r[4], r[6], false); ce(r[5], r[7], false);
  ce(r[0], r[1], true);  ce(r[2], r[3], true);
  ce(r[4], r[5], false); ce(r[6], r[7], false);
  // ---- k=8 (j=4,2,1): dir = ((i&8)==0) = ((t&1)==0), uniform in thread ----
  {
    const bool up = ((t & 1) == 0);
    ce(r[0], r[4], up); ce(r[1], r[5], up); ce(r[2], r[6], up); ce(r[3], r[7], up);
    ce(r[0], r[2], up); ce(r[1], r[3], up); ce(r[4], r[6], up); ce(r[5], r[7], up);
    ce(r[0], r[1], up); ce(r[2], r[3], up); ce(r[4], r[5], up); ce(r[6], r[7], up);
  }

  // ---- k = 16..2048: thread-space k is tk = k/8 in {2..256} ----
  for (int tk = 2; tk <= 256; tk <<= 1) {
    const bool up = ((t & tk) == 0);  // ((i & k) == 0), k = 8*tk
    for (int m = tk >> 1; m >= 1; m >>= 1) {   // element stride j = 8m
      const bool keepMin = (((t & m) == 0) == up);
      if (m >= 64) {
        // cross-wave: exchange via LDS, transposed layout (unit-stride).
        __syncthreads();
#pragma unroll
        for (int o = 0; o < EPT; ++o) lds[o * BLK + t] = r[o];
        __syncthreads();
#pragma unroll
        for (int o = 0; o < EPT; ++o) {
          const uint64_t th = lds[o * BLK + (t ^ m)];
          const uint64_t mn = (r[o] < th) ? r[o] : th;
          const uint64_t mx = (r[o] < th) ? th : r[o];
          r[o] = keepMin ? mn : mx;
        }
      } else {
        // same-wave: register exchange via shuffle.
#pragma unroll
        for (int o = 0; o < EPT; ++o) {
          const uint64_t th = shfl_xor_u64(r[o], m);
          const uint64_t mn = (r[o] < th) ? r[o] : th;
          const uint64_t mx = (r[o] < th) ? th : r[o];
          r[o] = keepMin ? mn : mx;
        }
      }
    }
    // intra-thread tail: j = 4, 2, 1, uniform direction `up`.
    ce(r[0], r[4], up); ce(r[1], r[5], up); ce(r[2], r[6], up); ce(r[3], r[7], up);
    ce(r[0], r[2], up); ce(r[1], r[3], up); ce(r[4], r[6], up); ce(r[5], r[7], up);
    ce(r[0], r[1], up); ce(r[2], r[3], up); ce(r[4], r[5], up); ce(r[6], r[7], up);
  }

  // Emit: thread t holds ranks 8t..8t+7. (out+off is only 4B-aligned, so
  // scalar int stores; output is ~13 MB, HBM is ~1% busy — not the lever.)
  const int L = base[v];
#pragma unroll
  for (int o = 0; o < EPT; ++o) {
    const int rank = t * EPT + o;
    if (rank < D) out[off + rank] = (rank < L) ? (int)(r[o] & 2047u) : 0;
  }
}

extern "C" void kernel_launch(void* const* d_in, const int* in_sizes, int n_in,
                              void* d_out, int out_size, void* d_ws, size_t ws_size,
                              hipStream_t stream) {
  const float* to_cut = (const float*)d_in[0];
  const int*   base   = (const int*)d_in[1];
  // ids = repeat(arange(P), T) sorted -> lens[flat v] == base[v]; no segment pass.
  const int N = in_sizes[1];      // visits (P*T)
  const int D = in_sizes[0] / N;  // codes per visit

  cutout_sort_kernel<<<dim3(N), dim3(BLK), 0, stream>>>(
      to_cut, base, (int*)d_out, D);
}

// Round 5
// 287.884 us; speedup vs baseline: 1.3158x; 1.1403x over previous
//
#include <hip/hip_runtime.h>
#include <stdint.h>

// CutOutput: per visit v (8192), stable descending argsort of D=1571 f32
// scores; emit index order, zeroing ranks >= L = base[v].
//
// key = (~orderable(f) << 11) | index  — ascending u64 == descending f32,
// ties broken by ascending index (bit-exact vs JAX stable argsort of -x).
//
// Bitonic-2048, register-resident: thread t owns elements 8t..8t+7.
//   elem stride 1,2,4    -> in-register CE
//   elem stride 8..256   -> ds_bpermute with hoisted lane addr (same wave)
//   elem stride 512,1024 -> LDS exchange (3 passes), transposed layout
// All passes fully unrolled via template<int TK> so direction/keep masks and
// bpermute addresses are hoisted; exchange is the single-select form
// r = ((r<th)==keep) ? r : th  (keys strictly distinct — index bits differ).

#define BLK   256
#define NSORT 2048
#define EPT   8

__device__ __forceinline__ uint64_t bperm64(int addr, uint64_t x) {
  int lo = __builtin_amdgcn_ds_bpermute(addr, (int)(uint32_t)x);
  int hi = __builtin_amdgcn_ds_bpermute(addr, (int)(uint32_t)(x >> 32));
  return ((uint64_t)(uint32_t)hi << 32) | (uint32_t)lo;
}

__device__ __forceinline__ void ce(uint64_t& a, uint64_t& b, bool up) {
  const bool c = a < b;
  const uint64_t lo = c ? a : b;
  const uint64_t hi = c ? b : a;
  a = up ? lo : hi;
  b = up ? hi : lo;
}

template<int TK>
__device__ __forceinline__ void merge_step(uint64_t r[EPT], const int t,
                                           const int lane4, uint64_t* lds) {
  const bool up = ((t & TK) == 0);   // bitonic direction, k = 8*TK
#pragma unroll
  for (int m = TK >> 1; m >= 1; m >>= 1) {        // element stride j = 8m
    const bool keep = (((t & m) == 0) == up);     // this thread keeps min?
    if (m >= 64) {
      // cross-wave: LDS exchange, transposed layout (unit-stride, no conflict)
      __syncthreads();
#pragma unroll
      for (int o = 0; o < EPT; ++o) lds[o * BLK + t] = r[o];
      __syncthreads();
#pragma unroll
      for (int o = 0; o < EPT; ++o) {
        const uint64_t th = lds[o * BLK + (t ^ m)];
        r[o] = ((r[o] < th) == keep) ? r[o] : th;
      }
    } else {
      // same-wave: bpermute, one byte-address per pass shared by 16 words
      const int addr = lane4 ^ (m << 2);
#pragma unroll
      for (int o = 0; o < EPT; ++o) {
        const uint64_t th = bperm64(addr, r[o]);
        r[o] = ((r[o] < th) == keep) ? r[o] : th;
      }
    }
  }
  // intra-thread tail: element strides 4,2,1, uniform direction `up`
  ce(r[0], r[4], up); ce(r[1], r[5], up); ce(r[2], r[6], up); ce(r[3], r[7], up);
  ce(r[0], r[2], up); ce(r[1], r[3], up); ce(r[4], r[6], up); ce(r[5], r[7], up);
  ce(r[0], r[1], up); ce(r[2], r[3], up); ce(r[4], r[5], up); ce(r[6], r[7], up);
}

__global__ __launch_bounds__(BLK, 8) void cutout_sort_kernel(
    const float* __restrict__ to_cut,
    const int*  __restrict__ base,
    int*        __restrict__ out,
    int D) {
  __shared__ uint64_t lds[NSORT];
  const int    t     = threadIdx.x;
  const int    lane4 = (t & 63) << 2;
  const int    v     = blockIdx.x;
  const size_t off   = (size_t)v * (size_t)D;

  // Load + pack. Pad (e >= D) with max key so padding sorts to the end.
  uint64_t r[EPT];
#pragma unroll
  for (int o = 0; o < EPT; ++o) {
    const int e = t * EPT + o;
    uint64_t key = ~0ull;
    if (e < D) {
      unsigned u = __float_as_uint(to_cut[off + e]);
      u = (u & 0x80000000u) ? ~u : (u | 0x80000000u);  // ascending-orderable
      key = ((uint64_t)(unsigned)(~u) << 11) | (unsigned)e;
    }
    r[o] = key;
  }

  // k=2 (elem stride 1): direction depends on o only
  ce(r[0], r[1], true);  ce(r[2], r[3], false);
  ce(r[4], r[5], true);  ce(r[6], r[7], false);
  // k=4 (strides 2,1)
  ce(r[0], r[2], true);  ce(r[1], r[3], true);
  ce(r[4], r[6], false); ce(r[5], r[7], false);
  ce(r[0], r[1], true);  ce(r[2], r[3], true);
  ce(r[4], r[5], false); ce(r[6], r[7], false);
  // k=8 (strides 4,2,1): direction uniform within thread
  {
    const bool up = ((t & 1) == 0);
    ce(r[0], r[4], up); ce(r[1], r[5], up); ce(r[2], r[6], up); ce(r[3], r[7], up);
    ce(r[0], r[2], up); ce(r[1], r[3], up); ce(r[4], r[6], up); ce(r[5], r[7], up);
    ce(r[0], r[1], up); ce(r[2], r[3], up); ce(r[4], r[5], up); ce(r[6], r[7], up);
  }

  // k = 16..2048 in thread-space TK = k/8
  merge_step<2>(r, t, lane4, lds);
  merge_step<4>(r, t, lane4, lds);
  merge_step<8>(r, t, lane4, lds);
  merge_step<16>(r, t, lane4, lds);
  merge_step<32>(r, t, lane4, lds);
  merge_step<64>(r, t, lane4, lds);
  merge_step<128>(r, t, lane4, lds);
  merge_step<256>(r, t, lane4, lds);

  // Emit: thread t holds ranks 8t..8t+7.
  const int L = base[v];
#pragma unroll
  for (int o = 0; o < EPT; ++o) {
    const int rank = t * EPT + o;
    if (rank < D) out[off + rank] = (rank < L) ? (int)(r[o] & 2047u) : 0;
  }
}

extern "C" void kernel_launch(void* const* d_in, const int* in_sizes, int n_in,
                              void* d_out, int out_size, void* d_ws, size_t ws_size,
                              hipStream_t stream) {
  const float* to_cut = (const float*)d_in[0];
  const int*   base   = (const int*)d_in[1];
  // ids = repeat(arange(P), T) sorted -> lens[flat v] == base[v]; no segment pass.
  const int N = in_sizes[1];      // visits (P*T)
  const int D = in_sizes[0] / N;  // codes per visit

  cutout_sort_kernel<<<dim3(N), dim3(BLK), 0, stream>>>(
      to_cut, base, (int*)d_out, D);
}

// Round 6
// 223.267 us; speedup vs baseline: 1.6967x; 1.2894x over previous
//
#include <hip/hip_runtime.h>
#include <stdint.h>

// CutOutput: per visit v (8192), stable descending argsort of D=1571 f32
// scores; emit index order, zeroing ranks >= L = base[v].
//
// Stable LSD radix sort, 4 passes x 8-bit digits over key32 = ~orderable(f)
// (ascending key == descending float). Index (11 bits) rides as a u16
// payload; LSD stability == JAX argsort tie-break by index, bit-exact,
// WITHOUT 64-bit keys.
//
// Per pass (256 thr, 8 elem/thr, 2048 slots in LDS ping-pong):
//   - element order = position p = 512*wave + 64*round + lane (increasing ->
//     stability holds across rounds/lanes/waves)
//   - rank within wave via 8-ballot digit match + popc(mask & lanes_below)
//   - per-wave 256-bin histogram in LDS (leader lane updates running count)
//   - 256-bin block scan (wave 0: 4 bins/lane + shfl_up scan)
//   - scatter (key,idx) to computed destination in the other buffer
// Pads (e >= D) carry key 0xFFFFFFFF -> sort strictly last (real keys can't
// reach 0xFFFFFFFF: that would need f = -inf).

#define BLK   256
#define NSORT 2048
#define EPT   8

__global__ __launch_bounds__(BLK, 5) void cutout_radix_kernel(
    const float* __restrict__ to_cut,
    const int*  __restrict__ base,
    int*        __restrict__ out,
    int D) {
  __shared__ uint32_t kbuf[2][NSORT];   // 16 KB
  __shared__ uint16_t ibuf[2][NSORT];   //  8 KB
  __shared__ uint32_t hist[4 * 256];    //  4 KB
  __shared__ uint32_t sbuf[256];        //  1 KB

  const int      t    = threadIdx.x;
  const int      lane = t & 63;
  const int      w    = t >> 6;
  const int      v    = blockIdx.x;
  const size_t   off  = (size_t)v * (size_t)D;
  const uint64_t lt   = (1ull << lane) - 1;   // lanes below me

  // Load + pack into buffer 0 (coalesced).
#pragma unroll
  for (int o = 0; o < EPT; ++o) {
    const int e = o * BLK + t;
    uint32_t key = 0xFFFFFFFFu;
    if (e < D) {
      uint32_t u = __float_as_uint(to_cut[off + e]);
      u = (u & 0x80000000u) ? ~u : (u | 0x80000000u);  // ascending-orderable
      key = ~u;                                        // ascending == descending f32
    }
    kbuf[0][e] = key;
    ibuf[0][e] = (uint16_t)e;
  }

  int cur = 0;
#pragma unroll
  for (int p = 0; p < 4; ++p) {
    const int shift = 8 * p;
    uint32_t* kin  = kbuf[cur];
    uint16_t* iin  = ibuf[cur];
    uint32_t* kout = kbuf[cur ^ 1];
    uint16_t* iout = ibuf[cur ^ 1];

    // Zero histogram. Barrier also covers prev-pass scatter (and the initial
    // load for p==0).
#pragma unroll
    for (int q = 0; q < 4; ++q) hist[q * 256 + t] = 0;
    __syncthreads();

    // Gather (conflict-free: consecutive lanes -> consecutive addrs).
    uint32_t key[EPT], idx[EPT], dig[EPT], rnk[EPT];
#pragma unroll
    for (int o = 0; o < EPT; ++o) {
      const int pos = w * 512 + o * 64 + lane;
      key[o] = kin[pos];
      idx[o] = iin[pos];
      dig[o] = (key[o] >> shift) & 255u;
    }

    // Rank: rounds o processed in order; hist[w][d] is the running count of
    // digit d in this wave over earlier rounds. Ballot-match gives same-digit
    // lanes this round; rank = running + lanes-below-me. Lowest matching lane
    // (leader) bumps the running count. All-lane-active uniform flow.
#pragma unroll
    for (int o = 0; o < EPT; ++o) {
      uint64_t m = ~0ull;
#pragma unroll
      for (int b = 0; b < 8; ++b) {
        const uint32_t bit = (dig[o] >> b) & 1u;
        const uint64_t bb  = __ballot(bit);
        m &= bit ? bb : ~bb;
      }
      const uint32_t before = __popcll(m & lt);
      const uint32_t cnt    = __popcll(m);
      const uint32_t b0     = hist[w * 256 + dig[o]];
      if (before == 0) hist[w * 256 + dig[o]] = b0 + cnt;  // leader updates
      rnk[o] = b0 + before;
    }
    __syncthreads();

    // Block scan over 256 digit totals.
    {
      const uint32_t c0 = hist[0 * 256 + t], c1 = hist[1 * 256 + t];
      const uint32_t c2 = hist[2 * 256 + t], c3 = hist[3 * 256 + t];
      sbuf[t] = c0 + c1 + c2 + c3;
    }
    __syncthreads();
    if (t < 64) {  // wave 0: lane handles digits 4t..4t+3
      const uint32_t c0 = sbuf[4 * t + 0], c1 = sbuf[4 * t + 1];
      const uint32_t c2 = sbuf[4 * t + 2], c3 = sbuf[4 * t + 3];
      const uint32_t s  = c0 + c1 + c2 + c3;
      uint32_t vs = s;
#pragma unroll
      for (int d = 1; d < 64; d <<= 1) {
        const uint32_t u = __shfl_up(vs, d, 64);
        if (lane >= d) vs += u;
      }
      const uint32_t ex = vs - s;  // exclusive prefix of 4-digit group
      sbuf[4 * t + 0] = ex;
      sbuf[4 * t + 1] = ex + c0;
      sbuf[4 * t + 2] = ex + c0 + c1;
      sbuf[4 * t + 3] = ex + c0 + c1 + c2;
    }
    __syncthreads();
    {
      // hist[w][d] <- global start for (wave w, digit d); read counts first.
      const uint32_t c0 = hist[0 * 256 + t], c1 = hist[1 * 256 + t];
      const uint32_t c2 = hist[2 * 256 + t];
      uint32_t run = sbuf[t];
      hist[0 * 256 + t] = run; run += c0;
      hist[1 * 256 + t] = run; run += c1;
      hist[2 * 256 + t] = run; run += c2;
      hist[3 * 256 + t] = run;
    }
    __syncthreads();

    // Scatter to destination (stable).
#pragma unroll
    for (int o = 0; o < EPT; ++o) {
      const uint32_t dest = hist[w * 256 + dig[o]] + rnk[o];
      kout[dest] = key[o];
      iout[dest] = (uint16_t)idx[o];
    }
    cur ^= 1;
  }
  __syncthreads();  // final scatter visible

  // Emit: rank r holds original index ibuf[0][r] (cur is 0 after 4 passes);
  // zero for r >= L.
  const int L = base[v];
#pragma unroll
  for (int o = 0; o < EPT; ++o) {
    const int r = o * BLK + t;
    if (r < D) out[off + r] = (r < L) ? (int)ibuf[0][r] : 0;
  }
}

extern "C" void kernel_launch(void* const* d_in, const int* in_sizes, int n_in,
                              void* d_out, int out_size, void* d_ws, size_t ws_size,
                              hipStream_t stream) {
  const float* to_cut = (const float*)d_in[0];
  const int*   base   = (const int*)d_in[1];
  // ids = repeat(arange(P), T) sorted -> lens[flat v] == base[v]; no segment pass.
  const int N = in_sizes[1];      // visits (P*T)
  const int D = in_sizes[0] / N;  // codes per visit

  cutout_radix_kernel<<<dim3(N), dim3(BLK), 0, stream>>>(
      to_cut, base, (int*)d_out, D);
}

// Round 10
// 206.073 us; speedup vs baseline: 1.8382x; 1.0834x over previous
//
#include <hip/hip_runtime.h>
#include <stdint.h>

// CutOutput: per visit v (8192), stable descending argsort of D=1571 f32
// scores; emit index order, zeroing ranks >= L = base[v].
//
// key32 = ~orderable(f): ascending key == descending f32. LSD-radix
// stability == JAX tie-break by index (index rides as u16 payload).
//
// This is the round-6 PROVEN 4-pass ballot radix with one change: the sort
// length is M = roundup(D,256) = RCT*256 chosen at COMPILE TIME per
// instantiation (host switch on R = M/256). For D=1571: RCT=7, M=1792
// (vs fixed 2048) -> 7/8 the radix work, smaller LDS (26.6 KB -> 6
// blocks/CU). No runtime-R guards anywhere (the three failed pruning
// attempts all shared runtime-variable sort length; R is now a template
// constant folded at compile time).
//
// Sentinels 0xFFFFFFFF fill [D, M): sort strictly last (a real key of
// ~orderable(f) can't be all-ones barring -inf/NaN, absent here), and ranks
// [D, M) are never emitted since L <= D-1.

#define BLK 256
#define EPT 8

template<int RCT>
__global__ __launch_bounds__(BLK, 5) void cutout_radix_ct(
    const float* __restrict__ to_cut,
    const int*  __restrict__ base,
    int*        __restrict__ out,
    int D) {
  constexpr int MCT = RCT * 256;   // sort length
  constexpr int WSH = RCT * 64;    // elements per wave
  __shared__ uint32_t kbuf[2][MCT];
  __shared__ uint16_t ibuf[2][MCT];
  __shared__ uint32_t hist[4 * 256];
  __shared__ uint32_t sbuf[256];

  const int      t    = threadIdx.x;
  const int      lane = t & 63;
  const int      w    = t >> 6;
  const int      v    = blockIdx.x;
  const size_t   off  = (size_t)v * (size_t)D;
  const uint64_t lt   = (1ull << lane) - 1;

  // ---- Load + pack into buffer 0 (coalesced); covers exactly [0, MCT).
#pragma unroll
  for (int o = 0; o < RCT; ++o) {
    const int e = o * BLK + t;
    uint32_t key = 0xFFFFFFFFu;
    if (e < D) {
      uint32_t u = __float_as_uint(to_cut[off + e]);
      u = (u & 0x80000000u) ? ~u : (u | 0x80000000u);  // ascending-orderable
      key = ~u;                                        // ascending == desc f32
    }
    kbuf[0][e] = key;
    ibuf[0][e] = (uint16_t)e;
  }

  // ---- 4-pass LSD ballot radix over [0, MCT) (round-6 structure).
  int cur = 0;
#pragma unroll
  for (int pass = 0; pass < 4; ++pass) {
    const int  shift = 8 * pass;
    uint32_t*  kin   = kbuf[cur];
    uint16_t*  iin   = ibuf[cur];
    uint32_t*  kout  = kbuf[cur ^ 1];
    uint16_t*  iout  = ibuf[cur ^ 1];

#pragma unroll
    for (int q = 0; q < 4; ++q) hist[q * 256 + t] = 0;
    __syncthreads();  // also covers prev-pass scatter / initial load

    // Gather in position order: pos = w*WSH + o*64 + lane.
    uint32_t key[RCT], idx[RCT], dig[RCT], rnk[RCT];
#pragma unroll
    for (int o = 0; o < RCT; ++o) {
      const int pos = w * WSH + o * 64 + lane;
      key[o] = kin[pos];
      idx[o] = iin[pos];
      dig[o] = (key[o] >> shift) & 255u;
    }

    // Rank within wave: ballot digit-match; leader bumps running count.
#pragma unroll
    for (int o = 0; o < RCT; ++o) {
      uint64_t mm = ~0ull;
#pragma unroll
      for (int b = 0; b < 8; ++b) {
        const uint32_t bit = (dig[o] >> b) & 1u;
        const uint64_t bb  = __ballot(bit);
        mm &= bit ? bb : ~bb;
      }
      const uint32_t before = (uint32_t)__popcll(mm & lt);
      const uint32_t cnt    = (uint32_t)__popcll(mm);
      const uint32_t b0     = hist[w * 256 + dig[o]];
      if (before == 0) hist[w * 256 + dig[o]] = b0 + cnt;  // leader updates
      rnk[o] = b0 + before;
    }
    __syncthreads();

    // Block scan of 256 digit totals.
    sbuf[t] = hist[0 * 256 + t] + hist[1 * 256 + t] +
              hist[2 * 256 + t] + hist[3 * 256 + t];
    __syncthreads();
    if (t < 64) {
      const uint32_t c0 = sbuf[4 * t + 0], c1 = sbuf[4 * t + 1];
      const uint32_t c2 = sbuf[4 * t + 2], c3 = sbuf[4 * t + 3];
      const uint32_t s  = c0 + c1 + c2 + c3;
      uint32_t vs = s;
#pragma unroll
      for (int d = 1; d < 64; d <<= 1) {
        const uint32_t u2 = __shfl_up(vs, d, 64);
        if (lane >= d) vs += u2;
      }
      const uint32_t ex = vs - s;
      sbuf[4 * t + 0] = ex;
      sbuf[4 * t + 1] = ex + c0;
      sbuf[4 * t + 2] = ex + c0 + c1;
      sbuf[4 * t + 3] = ex + c0 + c1 + c2;
    }
    __syncthreads();
    {
      const uint32_t c0 = hist[0 * 256 + t], c1 = hist[1 * 256 + t];
      const uint32_t c2 = hist[2 * 256 + t];
      uint32_t run = sbuf[t];
      hist[0 * 256 + t] = run; run += c0;
      hist[1 * 256 + t] = run; run += c1;
      hist[2 * 256 + t] = run; run += c2;
      hist[3 * 256 + t] = run;
    }
    __syncthreads();

    // Scatter (stable).
#pragma unroll
    for (int o = 0; o < RCT; ++o) {
      const uint32_t dest = hist[w * 256 + dig[o]] + rnk[o];
      kout[dest] = key[o];
      iout[dest] = (uint16_t)idx[o];
    }
    cur ^= 1;
  }
  __syncthreads();  // final scatter visible

  // ---- Emit: rank r holds original index ibuf[0][r]; zero for r >= L.
  const int L = base[v];
#pragma unroll
  for (int o = 0; o < RCT; ++o) {
    const int r = o * BLK + t;
    if (r < D) out[off + r] = (r < L) ? (int)ibuf[0][r] : 0;
  }
}

extern "C" void kernel_launch(void* const* d_in, const int* in_sizes, int n_in,
                              void* d_out, int out_size, void* d_ws, size_t ws_size,
                              hipStream_t stream) {
  const float* to_cut = (const float*)d_in[0];
  const int*   base   = (const int*)d_in[1];
  // ids = repeat(arange(P), T) sorted -> lens[flat v] == base[v]; no segment pass.
  const int N = in_sizes[1];      // visits (P*T)
  const int D = in_sizes[0] / N;  // codes per visit (1571 -> R=7)

  int* outp = (int*)d_out;
  const int R = ((D + 255) & ~255) >> 8;
  switch (R) {
    case 1: cutout_radix_ct<1><<<dim3(N), dim3(BLK), 0, stream>>>(to_cut, base, outp, D); break;
    case 2: cutout_radix_ct<2><<<dim3(N), dim3(BLK), 0, stream>>>(to_cut, base, outp, D); break;
    case 3: cutout_radix_ct<3><<<dim3(N), dim3(BLK), 0, stream>>>(to_cut, base, outp, D); break;
    case 4: cutout_radix_ct<4><<<dim3(N), dim3(BLK), 0, stream>>>(to_cut, base, outp, D); break;
    case 5: cutout_radix_ct<5><<<dim3(N), dim3(BLK), 0, stream>>>(to_cut, base, outp, D); break;
    case 6: cutout_radix_ct<6><<<dim3(N), dim3(BLK), 0, stream>>>(to_cut, base, outp, D); break;
    case 7: cutout_radix_ct<7><<<dim3(N), dim3(BLK), 0, stream>>>(to_cut, base, outp, D); break;
    default: cutout_radix_ct<8><<<dim3(N), dim3(BLK), 0, stream>>>(to_cut, base, outp, D); break;
  }
}